// Round 16
// baseline (221.251 us; speedup 1.0000x reference)
//
#include <hip/hip_runtime.h>
#include <hip/hip_bf16.h>

// SphericalAttention on MI355X (gfx950).  ROUND 34: R33 (green, 218.8us; attn
// 105.3 flat, bank-conflicts 1.5M->459K) -> attn is at its structural floor
// (5th null from a 5th mechanism; all pipes <40%). This round attacks the
// ~111us non-attn side: dist (trans/VALU-bound) and qkv_gemm (MFMA/mem-bound)
// are mutually independent -> FUSE into one heterogeneous grid (qkv blocks
// 0..1535 first, dist blocks 1536..5631) so the two profiles co-schedule:
// max(A,B) instead of A+B. cvt runs as a small standalone kernel ahead
// (feeds qkv); stats back to its own tiny launch (needs all dist partials).
// attn + out_gemm = R33 verbatim (register-P, conflict-free).
// Inputs fp32; output fp32. N=4096, C=512, nh=8, dh=64.

typedef __attribute__((ext_vector_type(8))) short bf16x8;
typedef __attribute__((ext_vector_type(4))) float f32x4;

#define MFMA16(a, b, c) __builtin_amdgcn_mfma_f32_16x16x32_bf16(a, b, c, 0, 0, 0)

__device__ __forceinline__ unsigned short f2b(float f) {
    union { float f; unsigned int i; } v;
    v.f = f;
    unsigned int lsb = (v.i >> 16) & 1u;
    unsigned int r = v.i + 0x7fffu + lsb;   // RNE
    return (unsigned short)(r >> 16);
}

// ------------------------------------------------- fp32 -> bf16, fragment order
// off(row,kcol) = g*8192 + c*512 + qd*128 + l*8 + e  (g=row>>4, l=row&15,
// c=kcol>>5, qd=(kcol>>3)&3, e=kcol&7). Grid 1536: b<1024 x, <1408 wq, else wo.
__global__ __launch_bounds__(256) void cvt_kernel(
    const float* __restrict__ x, unsigned short* __restrict__ xb,
    const float* __restrict__ wq, unsigned short* __restrict__ wqb,
    const float* __restrict__ wo, unsigned short* __restrict__ wob) {
    int b = blockIdx.x, tid = threadIdx.x;
    const float* in; unsigned short* out; int t;
    if (b < 1024)      { in = x;  out = xb;  t = b * 256 + tid; }
    else if (b < 1408) { in = wq; out = wqb; t = (b - 1024) * 256 + tid; }
    else               { in = wo; out = wob; t = (b - 1408) * 256 + tid; }
    int l = t & 15, qd = (t >> 4) & 3, c = (t >> 6) & 15, g = t >> 10;
    const float* src = in + ((size_t)g * 16 + l) * 512 + c * 32 + qd * 8;
    float4 v0 = *(const float4*)src;
    float4 v1 = *(const float4*)(src + 4);
    ushort4 u0, u1;
    u0.x = f2b(v0.x); u0.y = f2b(v0.y); u0.z = f2b(v0.z); u0.w = f2b(v0.w);
    u1.x = f2b(v1.x); u1.y = f2b(v1.y); u1.z = f2b(v1.z); u1.w = f2b(v1.w);
    unsigned short* dst = out + (size_t)t * 8;
    *(ushort4*)dst = u0;
    *(ushort4*)(dst + 4) = u1;
}

// -------------------------------------- fused dist + QKV GEMM (heterogeneous)
// blocks 0..1535: qkv_gemm tile (bx = i%24: <8 Q, <16 K, else V; by = i/24).
// blocks 1536..5631: dist tile + stats partials (fp32 in-loop accum).
// dist TILE-LINEAR: tile (i>>4, j>>6) = 1024 floats at ((i>>4)*64+(j>>6))<<10;
// within-tile (q=i&15, jl=j&63): (jl>>4)*256 + ((jl>>2)&3)*64 + (i&15)*4 + (jl&3).
// K/V fragment order (1KB lane-bursts); V carries register-P slot perm
// slot(t)=((t>>2)&3)*8+((t>>4)&1)*4+(t&3)+(t>>5)*32. q pre-scaled by 0.125.
__global__ __launch_bounds__(256) void dist_qkv_kernel(
    const float* __restrict__ lat, const float* __restrict__ lon,
    float* __restrict__ dist, double* __restrict__ partials,
    const unsigned short* __restrict__ x, const unsigned short* __restrict__ w,
    const float* __restrict__ b,
    unsigned short* __restrict__ q, unsigned short* __restrict__ k,
    unsigned short* __restrict__ vt) {
    __shared__ unsigned short stage[64][72];   // 9216 B (qkv branch)
    __shared__ float sl_i[64], sc_i[64], so_i[64];
    __shared__ float sl_j[64], sc_j[64], so_j[64];
    __shared__ double rs[256], rs2[256];

    int blk = blockIdx.x;
    int tid = threadIdx.x;

    if (blk >= 1536) {                     // ---------------- dist branch
        int db = blk - 1536;
        int i0 = (db >> 6) << 6;
        int j0 = (db & 63) << 6;

        if (tid < 64) {
            float la = lat[i0 + tid];
            sl_i[tid] = la; sc_i[tid] = __cosf(la); so_i[tid] = lon[i0 + tid];
        } else if (tid < 128) {
            int t = tid - 64;
            float la = lat[j0 + t];
            sl_j[t] = la; sc_j[t] = __cosf(la); so_j[t] = lon[j0 + t];
        }
        __syncthreads();

        float s = 0.f, s2 = 0.f;
        int col = tid & 63;
        int colpart = ((col >> 4) << 8) + (((col >> 2) & 3) << 6) + (col & 3);
        size_t tbase = ((size_t)(j0 >> 6) << 10) + colpart;
        float latj = sl_j[col], cj = sc_j[col], lonj = so_j[col];
#pragma unroll
        for (int kk = 0; kk < 16; kk++) {
            int row = (kk << 2) + (tid >> 6);
            float dlat = latj - sl_i[row];
            float dlon = lonj - so_i[row];
            float h1 = __sinf(0.5f * dlat);
            float h2 = __sinf(0.5f * dlon);
            float a = h1 * h1 + sc_i[row] * cj * h2 * h2;
            a = fminf(fmaxf(a, 0.0f), 1.0f);
            float d = 2.0f * asinf(sqrtf(a));
            dist[tbase + ((size_t)((i0 >> 4) + (row >> 4)) << 16)
                 + ((row & 15) << 2)] = d;
            s += d;
            s2 += d * d;
        }
        rs[tid] = (double)s; rs2[tid] = (double)s2;
        __syncthreads();
        for (int off = 128; off > 0; off >>= 1) {
            if (tid < off) { rs[tid] += rs[tid + off]; rs2[tid] += rs2[tid + off]; }
            __syncthreads();
        }
        if (tid == 0) {
            partials[2 * db] = rs[0];
            partials[2 * db + 1] = rs2[0];
        }
        return;
    }

    // ---------------- qkv branch
    int by = blk / 24;
    int bx = blk - by * 24;
    int lane = tid & 63, wave = tid >> 6;
    int l16 = lane & 15, quad = lane >> 4;
    int m0 = by * 64 + wave * 16;
    int n0 = bx * 64;

    const unsigned short* abase = x + (size_t)(by * 4 + wave) * 8192 + lane * 8;
    f32x4 acc[4];
#pragma unroll
    for (int nb = 0; nb < 4; nb++) acc[nb] = (f32x4){0.f, 0.f, 0.f, 0.f};

    for (int k0 = 0; k0 < 512; k0 += 32) {
        bf16x8 af = *(const bf16x8*)(abase + (k0 >> 5) * 512);
#pragma unroll
        for (int nb = 0; nb < 4; nb++) {
            bf16x8 bf = *(const bf16x8*)(w + (size_t)((n0 >> 4) + nb) * 8192
                                           + (k0 >> 5) * 512 + lane * 8);
            acc[nb] = MFMA16(af, bf, acc[nb]);
        }
    }
    if (bx < 8) {                          // Q blocks: direct store, old layout
#pragma unroll
        for (int nb = 0; nb < 4; nb++) {
            int jj = n0 + nb * 16 + l16;
            float bj = b[jj];
            int h = jj >> 6, d = jj & 63;
#pragma unroll
            for (int r = 0; r < 4; r++) {
                int n = m0 + quad * 4 + r;
                q[((size_t)h * 4096 + n) * 64 + d] = f2b((acc[nb][r] + bj) * 0.125f);
            }
        }
    } else if (bx < 16) {                  // K block: one head, fragment layout
        int h = bx - 8;
#pragma unroll
        for (int nb = 0; nb < 4; nb++) {
            int d = nb * 16 + l16;
            float bj = b[512 + h * 64 + d];
#pragma unroll
            for (int r = 0; r < 4; r++)
                stage[wave * 16 + quad * 4 + r][d] = f2b(acc[nb][r] + bj);
        }
        __syncthreads();
        unsigned short* kb = k + ((size_t)h << 18) + (size_t)by * 4096;
#pragma unroll
        for (int p = 0; p < 2; p++) {
            int rid = p * 256 + tid;              // 0..511
            int t = rid >> 7;                     // tile (16 rows)
            int rem = rid & 127;
            int half = rem >> 6, qd = (rem >> 4) & 3, l = rem & 15;
            const unsigned short* src = &stage[t * 16 + l][half * 32 + qd * 8];
            unsigned short* dst = kb + t * 1024 + half * 512 + qd * 128 + l * 8;
            *(uint4*)dst = *(const uint4*)src;
        }
    } else {                               // V block: transpose + slot perm
        int h = bx - 16;
#pragma unroll
        for (int nb = 0; nb < 4; nb++) {
            int d = nb * 16 + l16;
            float bj = b[1024 + h * 64 + d];
            // register-P slot: t=wave*16+quad*4+r ->
            //   quad*8 + (wave&1)*4 + r + (wave>>1)*32
#pragma unroll
            for (int r = 0; r < 4; r++)
                stage[d][quad * 8 + (wave & 1) * 4 + r + (wave >> 1) * 32] =
                    f2b(acc[nb][r] + bj);
        }
        __syncthreads();
        int t = tid;
        int d = t >> 2;                    // 0..63
        int nq = (t & 3) * 16;             // stored-slot run start
        unsigned short* dst = vt + ((size_t)h << 18) + (size_t)by * 4096
                            + (d >> 4) * 1024 + ((nq >> 5) & 1) * 512
                            + ((nq >> 3) & 3) * 128 + (d & 15) * 8;
        const unsigned short* src = &stage[d][nq];
        *(uint4*)dst = *(const uint4*)src;         // slots nq..nq+7
        *(uint4*)(dst + 128) = *(const uint4*)(src + 8);  // slots nq+8..nq+15
    }
}

__global__ __launch_bounds__(256) void stats_kernel(
    const double* __restrict__ partials, float* __restrict__ neg_inv_std) {
    __shared__ double rs[256], rs2[256];
    int tid = threadIdx.x;
    double s = 0.0, s2 = 0.0;
    for (int i = tid; i < 4096; i += 256) {
        s += partials[2 * i];
        s2 += partials[2 * i + 1];
    }
    rs[tid] = s; rs2[tid] = s2;
    __syncthreads();
    for (int off = 128; off > 0; off >>= 1) {
        if (tid < off) { rs[tid] += rs[tid + off]; rs2[tid] += rs2[tid + off]; }
        __syncthreads();
    }
    if (tid == 0) {
        double n = 16777216.0;
        double mean = rs[0] / n;
        double var = (rs2[0] - n * mean * mean) / (n - 1.0);  // ddof=1
        *neg_inv_std = (float)(-1.0 / sqrt(var));
    }
}

// ---------------------------------------------------------------- flash attention
// Block = 512 thr = 8 waves = (2 q-groups x 4 kv-quarters), 1 head x 32
// q-rows. Grid 1024. XCD swizzle: xcd=b&7, j=b>>3; h=(xcd&3)*2+(j&1);
// qs=(xcd>>2)*64+(j>>1). SWAPPED QK: s = MFMA(K,Q) -> lane holds
// P[kv=16cb+4quad+r][q=l16]; P packs directly into PV A-fragments (no LDS).
// Bias from tile-linear dist (1KB bursts), single-buffered in-step prefetch.
// V hoisted above exp; setprio around MFMA clusters. No max-subtraction.
// Epilogue writes att in FRAGMENT order (out_gemm A-operand).
__device__ __forceinline__ void attn_step(
    const unsigned short* __restrict__ kptr, const unsigned short* __restrict__ vtp,
    int h, int kv0, int lane,
    bf16x8 qf0, bf16x8 qf1, f32x4 (&dv)[4], const float* __restrict__ dbase,
    int kv_next, float nis, f32x4 (&o)[4], float& lam) {
    size_t tbase = ((size_t)h << 18) + ((size_t)kv0 << 6) + lane * 8;
    const unsigned short* kb = kptr + tbase;
    const unsigned short* vb = vtp + tbase;
    f32x4 s[4];
    __builtin_amdgcn_s_setprio(1);
#pragma unroll
    for (int cb = 0; cb < 4; cb++) {
        bf16x8 kf0 = *(const bf16x8*)(kb + cb * 1024);
        bf16x8 kf1 = *(const bf16x8*)(kb + cb * 1024 + 512);
        f32x4 z = (f32x4){0.f, 0.f, 0.f, 0.f};
        z = MFMA16(kf0, qf0, z);           // SWAPPED: K rows, Q cols
        z = MFMA16(kf1, qf1, z);
        s[cb] = z;
    }
    __builtin_amdgcn_s_setprio(0);
    // hoisted V fragment loads: latency hides under bias+exp+pack below
    bf16x8 vf[8];
#pragma unroll
    for (int db = 0; db < 4; db++) {
        vf[2 * db]     = *(const bf16x8*)(vb + db * 1024);
        vf[2 * db + 1] = *(const bf16x8*)(vb + db * 1024 + 512);
    }
    // bias: s[cb][r] += dist[q=l16][kv0+16cb+4quad+r]*nis  (dv[cb] float4)
#pragma unroll
    for (int cb = 0; cb < 4; cb++) {
        s[cb][0] = fmaf(dv[cb][0], nis, s[cb][0]);
        s[cb][1] = fmaf(dv[cb][1], nis, s[cb][1]);
        s[cb][2] = fmaf(dv[cb][2], nis, s[cb][2]);
        s[cb][3] = fmaf(dv[cb][3], nis, s[cb][3]);
    }
    // prefetch next step's bias (tile-linear: +1024 floats per kv-tile)
    {
        const float* dnext = dbase + ((size_t)(kv_next >> 6) << 10);
#pragma unroll
        for (int cb = 0; cb < 4; cb++)
            dv[cb] = *(const f32x4*)(dnext + cb * 256);
    }
    // exp (no max-sub), per-lane sum, pack P straight into A-fragments
    bf16x8 pf0, pf1;
#pragma unroll
    for (int cb = 0; cb < 4; cb++) {
        float p0 = __expf(s[cb][0]);
        float p1 = __expf(s[cb][1]);
        float p2 = __expf(s[cb][2]);
        float p3 = __expf(s[cb][3]);
        lam += (p0 + p1) + (p2 + p3);
        if (cb < 2) {
            pf0[cb * 4 + 0] = (short)f2b(p0);
            pf0[cb * 4 + 1] = (short)f2b(p1);
            pf0[cb * 4 + 2] = (short)f2b(p2);
            pf0[cb * 4 + 3] = (short)f2b(p3);
        } else {
            pf1[(cb - 2) * 4 + 0] = (short)f2b(p0);
            pf1[(cb - 2) * 4 + 1] = (short)f2b(p1);
            pf1[(cb - 2) * 4 + 2] = (short)f2b(p2);
            pf1[(cb - 2) * 4 + 3] = (short)f2b(p3);
        }
    }
    __builtin_amdgcn_s_setprio(1);
#pragma unroll
    for (int db = 0; db < 4; db++) {
        o[db] = MFMA16(pf0, vf[2 * db], o[db]);
        o[db] = MFMA16(pf1, vf[2 * db + 1], o[db]);
    }
    __builtin_amdgcn_s_setprio(0);
}

__global__ __launch_bounds__(512, 4) void attn_kernel(
    const unsigned short* __restrict__ q, const unsigned short* __restrict__ k,
    const unsigned short* __restrict__ vt, const float* __restrict__ dist,
    const float* __restrict__ nis_p, unsigned short* __restrict__ att) {
    __shared__ __align__(16) char smem[8704];    // obuf 8KB | lbuf 512B
    int tid = threadIdx.x;
    int lane = tid & 63, wave = tid >> 6;        // wave 0..7
    int l16 = lane & 15, quad = lane >> 4;
    int b = blockIdx.x;
    int xcd = b & 7, j = b >> 3;                 // j 0..127
    int h  = (xcd & 3) * 2 + (j & 1);            // head for whole block
    int qs = (xcd >> 2) * 64 + (j >> 1);         // 32-row q-group, 0..127
    int qgl = wave & 1;                          // local q-group (16 rows)
    int qt = wave >> 1;                          // kv quarter
    int q0 = qs * 32 + qgl * 16;
    int kvbase = qt * 1024;
    float nis = *nis_p;

    const unsigned short* qbase = q + ((size_t)h * 4096 + q0 + l16) * 64 + quad * 8;
    bf16x8 qf0 = *(const bf16x8*)(qbase);
    bf16x8 qf1 = *(const bf16x8*)(qbase + 32);

    f32x4 o[4];
    float lam = 0.f;
#pragma unroll
    for (int r = 0; r < 4; r++) {
        o[0][r] = 0.f; o[1][r] = 0.f; o[2][r] = 0.f; o[3][r] = 0.f;
    }

    // tile-linear dist base for this lane: tile row q0>>4, +quad*64+l16*4
    const float* dbase = dist + ((size_t)(q0 >> 4) << 16) + quad * 64 + l16 * 4;
    f32x4 dv[4];
    {
        const float* d0 = dbase + ((size_t)(kvbase >> 6) << 10);
#pragma unroll
        for (int cb = 0; cb < 4; cb++)
            dv[cb] = *(const f32x4*)(d0 + cb * 256);
    }

    for (int it = 0; it < 16; ++it) {
        int kv0 = kvbase + it * 64;
        int kvn = (it == 15) ? kvbase : kv0 + 64;
        attn_step(k, vt, h, kv0, lane, qf0, qf1, dv, dbase, kvn, nis, o, lam);
    }

    // row-sum: lane holds partial for q=l16; reduce across the 4 quads
    lam += __shfl_xor(lam, 16, 64);
    lam += __shfl_xor(lam, 32, 64);

    // -------- block-level merge across 4 kv-quarters: plain sums
    __syncthreads();
    float* obuf = (float*)smem;             // [2 qgl][16 row][64 d] = 8 KiB
    float* lbuf = (float*)(smem + 8192);    // [4 quarter][32 row]
    if (lane < 16)                          // quad==0 lanes hold final lam
        lbuf[qt * 32 + qgl * 16 + lane] = lam;
    if (qt == 0) {
#pragma unroll
        for (int db = 0; db < 4; db++)
#pragma unroll
            for (int r = 0; r < 4; r++)
                obuf[(qgl * 16 + quad * 4 + r) * 64 + db * 16 + l16] = o[db][r];
    }
    __syncthreads();
    if (qt == 1) {
#pragma unroll
        for (int db = 0; db < 4; db++)
#pragma unroll
            for (int r = 0; r < 4; r++)
                obuf[(qgl * 16 + quad * 4 + r) * 64 + db * 16 + l16] += o[db][r];
    }
    __syncthreads();
    if (qt == 2) {
#pragma unroll
        for (int db = 0; db < 4; db++)
#pragma unroll
            for (int r = 0; r < 4; r++)
                obuf[(qgl * 16 + quad * 4 + r) * 64 + db * 16 + l16] += o[db][r];
    }
    __syncthreads();
    if (qt == 3) {
#pragma unroll
        for (int db = 0; db < 4; db++)
#pragma unroll
            for (int r = 0; r < 4; r++)
                obuf[(qgl * 16 + quad * 4 + r) * 64 + db * 16 + l16] += o[db][r];
    }
    __syncthreads();

    // 512 threads write 32 rows x 64 cols (one head): 4 cols/thread,
    // att in FRAGMENT order: off = g*8192 + c*512 + qd*128 + l*8 + e
    int rl = tid >> 4;                  // 0..31 local row
    int d4 = (tid & 15) * 4;            // 0..60
    float L = lbuf[rl] + lbuf[32 + rl] + lbuf[64 + rl] + lbuf[96 + rl];
    float rinv = 1.0f / L;
    const float* ob = obuf + rl * 64 + d4;
    ushort4 ua;
    ua.x = f2b(ob[0] * rinv); ua.y = f2b(ob[1] * rinv);
    ua.z = f2b(ob[2] * rinv); ua.w = f2b(ob[3] * rinv);
    int row = qs * 32 + rl;
    int col = h * 64 + d4;
    size_t dst = (size_t)(row >> 4) * 8192 + (col >> 5) * 512
               + ((col >> 3) & 3) * 128 + (row & 15) * 8 + (col & 7);
    *(ushort4*)(att + dst) = ua;
}

// ---------------------------------------------------------------- output GEMM (fp32 store)
// att and w read in fragment order (contiguous lane*8 bursts).
__global__ __launch_bounds__(256) void out_gemm(
    const unsigned short* __restrict__ att, const unsigned short* __restrict__ w,
    const float* __restrict__ b, float* __restrict__ out) {
    int lane = threadIdx.x & 63, wave = threadIdx.x >> 6;
    int l16 = lane & 15, quad = lane >> 4;
    int m0 = blockIdx.y * 64 + wave * 16;
    int n0 = blockIdx.x * 64;

    const unsigned short* abase = att + (size_t)(blockIdx.y * 4 + wave) * 8192 + lane * 8;
    f32x4 acc[4];
#pragma unroll
    for (int nb = 0; nb < 4; nb++) acc[nb] = (f32x4){0.f, 0.f, 0.f, 0.f};

    for (int k0 = 0; k0 < 512; k0 += 32) {
        bf16x8 af = *(const bf16x8*)(abase + (k0 >> 5) * 512);
#pragma unroll
        for (int nb = 0; nb < 4; nb++) {
            bf16x8 bf = *(const bf16x8*)(w + (size_t)((n0 >> 4) + nb) * 8192
                                           + (k0 >> 5) * 512 + lane * 8);
            acc[nb] = MFMA16(af, bf, acc[nb]);
        }
    }
#pragma unroll
    for (int nb = 0; nb < 4; nb++) {
        float bj = b[n0 + nb * 16 + l16];
#pragma unroll
        for (int r = 0; r < 4; r++)
            out[(size_t)(m0 + quad * 4 + r) * 512 + n0 + nb * 16 + l16] =
                acc[nb][r] + bj;
    }
}

extern "C" void kernel_launch(void* const* d_in, const int* in_sizes, int n_in,
                              void* d_out, int out_size, void* d_ws, size_t ws_size,
                              hipStream_t stream) {
    const float* x    = (const float*)d_in[0];
    const float* lat  = (const float*)d_in[1];
    const float* lon  = (const float*)d_in[2];
    const float* wqkv = (const float*)d_in[3];
    const float* bqkv = (const float*)d_in[4];
    const float* wout = (const float*)d_in[5];
    const float* bout = (const float*)d_in[6];
    float* out = (float*)d_out;

    char* ws = (char*)d_ws;
    float* dist        = (float*)ws;                                  // 64 MiB
    double* partials   = (double*)(ws + 67108864);                    // 64 KiB
    float* nis         = (float*)(ws + 67108864 + 65536);             // 64 B
    unsigned short* q  = (unsigned short*)(ws + 67108864 + 65600);
    unsigned short* k  = q  + (size_t)8 * 4096 * 64;   // 4 MiB each
    unsigned short* vt = k  + (size_t)8 * 4096 * 64;
    unsigned short* att = vt + (size_t)8 * 4096 * 64;
    unsigned short* xb  = att + (size_t)4096 * 512;
    unsigned short* wqb = xb  + (size_t)4096 * 512;
    unsigned short* wob = wqb + (size_t)1536 * 512;

    cvt_kernel<<<1536, 256, 0, stream>>>(x, xb, wqkv, wqb, wout, wob);
    dist_qkv_kernel<<<5632, 256, 0, stream>>>(lat, lon, dist, partials,
                                              xb, wqb, bqkv, q, k, vt);
    stats_kernel<<<1, 256, 0, stream>>>(partials, nis);
    attn_kernel<<<1024, 512, 0, stream>>>(q, k, vt, dist, nis, att);
    out_gemm<<<dim3(8, 64), 256, 0, stream>>>(att, wob, bout, out);
}

// Round 17
// 212.487 us; speedup vs baseline: 1.0412x; 1.0412x over previous
//
#include <hip/hip_runtime.h>
#include <hip/hip_bf16.h>

// SphericalAttention on MI355X (gfx950).  ROUND 35: R34's dist+qkv fusion
// regressed (221.3 vs R32's 216.4; qkv lost L2 locality) -> revert to R32
// structure (best). attn = structural floor (6 mechanisms, 6 nulls). This
// round halves the dist trig: d(i,j)=d(j,i) BIT-EXACTLY in fp32 (sinf odd,
// h^2 even; products commutative). Prep computes only 2080 tile-pairs
// (ti<=tj): writes own tile coalesced, stages d in padded LDS [64][65]
// (conflict-free both ways), writes the mirror tile coalesced for ti!=tj;
// stats partials x2 for off-diagonal. Everything else = R32 verbatim
// (LDS-P attn + setprio + V-hoist, stats-in-qkv @ x==24 over 2080 partials,
// fragment-order GEMM operands).
// Inputs fp32; output fp32. N=4096, C=512, nh=8, dh=64.

typedef __attribute__((ext_vector_type(8))) short bf16x8;
typedef __attribute__((ext_vector_type(4))) float f32x4;

#define MFMA16(a, b, c) __builtin_amdgcn_mfma_f32_16x16x32_bf16(a, b, c, 0, 0, 0)

__device__ __forceinline__ unsigned short f2b(float f) {
    union { float f; unsigned int i; } v;
    v.f = f;
    unsigned int lsb = (v.i >> 16) & 1u;
    unsigned int r = v.i + 0x7fffu + lsb;   // RNE
    return (unsigned short)(r >> 16);
}

// --------------------------------------------- fused prep: dist(sym) + cvt x3
// blocks 0..2079: dist tile-PAIR (ti<=tj), both tiles written; partials x2
//   for off-diagonal. dist stored PERMUTED within each 64-col block:
//   col c -> (c&15)*4 + (c>>4).
// blocks 2080..3615: fp32->bf16 fragment-order cvt for x / wqkv / wout.
// Fragment order: off(row,kcol) = g*8192 + c*512 + qd*128 + l*8 + e.
__global__ __launch_bounds__(256) void prep_kernel(
    const float* __restrict__ lat, const float* __restrict__ lon,
    float* __restrict__ dist, double* __restrict__ partials,
    const float* __restrict__ x, unsigned short* __restrict__ xb,
    const float* __restrict__ wq, unsigned short* __restrict__ wqb,
    const float* __restrict__ wo, unsigned short* __restrict__ wob) {
    __shared__ float sl_i[64], sc_i[64], so_i[64];
    __shared__ float sl_j[64], sc_j[64], so_j[64];
    __shared__ float dstage[64][65];          // 16.6 KB, padded (conflict-free)
    __shared__ double rs[256], rs2[256];

    int b = blockIdx.x;
    int tid = threadIdx.x;

    if (b < 2080) {
        // unrank pair (ti <= tj) from b
        int ti = 0, rem = b;
        while (rem >= 64 - ti) { rem -= 64 - ti; ti++; }
        int tj = ti + rem;
        int i0 = ti << 6, j0 = tj << 6;

        if (tid < 64) {
            float la = lat[i0 + tid];
            sl_i[tid] = la; sc_i[tid] = __cosf(la); so_i[tid] = lon[i0 + tid];
        } else if (tid < 128) {
            int t = tid - 64;
            float la = lat[j0 + t];
            sl_j[t] = la; sc_j[t] = __cosf(la); so_j[t] = lon[j0 + t];
        }
        __syncthreads();

        float s = 0.f, s2 = 0.f;
        int col = tid & 63;
        int w = tid >> 6;
        int pcol = ((col & 15) << 2) + (col >> 4);   // permuted position
        float latj = sl_j[col], cj = sc_j[col], lonj = so_j[col];
#pragma unroll
        for (int kk = 0; kk < 16; kk++) {
            int row = (kk << 2) + w;
            float dlat = latj - sl_i[row];
            float dlon = lonj - so_i[row];
            float h1 = __sinf(0.5f * dlat);
            float h2 = __sinf(0.5f * dlon);
            float a = h1 * h1 + sc_i[row] * cj * h2 * h2;
            a = fminf(fmaxf(a, 0.0f), 1.0f);
            float d = 2.0f * asinf(sqrtf(a));
            dist[(size_t)(i0 + row) * 4096 + j0 + pcol] = d;
            dstage[row][col] = d;
            s += d;
            s2 += d * d;
        }
        if (ti != tj) {
            __syncthreads();
            // mirror tile (tj,ti): element (j0+row2, i0+col) = dstage[col][row2]
#pragma unroll
            for (int kk = 0; kk < 16; kk++) {
                int row2 = (kk << 2) + w;
                float dt = dstage[col][row2];    // stride-65 read: conflict-free
                dist[(size_t)(j0 + row2) * 4096 + i0 + pcol] = dt;
            }
            s *= 2.f; s2 *= 2.f;                 // values appear twice globally
        }
        rs[tid] = (double)s; rs2[tid] = (double)s2;
        __syncthreads();
        for (int off = 128; off > 0; off >>= 1) {
            if (tid < off) { rs[tid] += rs[tid + off]; rs2[tid] += rs2[tid + off]; }
            __syncthreads();
        }
        if (tid == 0) {
            partials[2 * b] = rs[0];
            partials[2 * b + 1] = rs2[0];
        }
        return;
    }

    // cvt branch
    const float* in; unsigned short* out; int t;
    if (b < 3104)      { in = x;  out = xb;  t = (b - 2080) * 256 + tid; }
    else if (b < 3488) { in = wq; out = wqb; t = (b - 3104) * 256 + tid; }
    else               { in = wo; out = wob; t = (b - 3488) * 256 + tid; }
    int l = t & 15, qd = (t >> 4) & 3, c = (t >> 6) & 15, g = t >> 10;
    const float* src = in + ((size_t)g * 16 + l) * 512 + c * 32 + qd * 8;
    float4 v0 = *(const float4*)src;
    float4 v1 = *(const float4*)(src + 4);
    ushort4 u0, u1;
    u0.x = f2b(v0.x); u0.y = f2b(v0.y); u0.z = f2b(v0.z); u0.w = f2b(v0.w);
    u1.x = f2b(v1.x); u1.y = f2b(v1.y); u1.z = f2b(v1.z); u1.w = f2b(v1.w);
    unsigned short* dst = out + (size_t)t * 8;
    *(ushort4*)dst = u0;
    *(ushort4*)(dst + 4) = u1;
}

// ---------------------------------------------------------------- QKV GEMM
// x and w read in fragment order (contiguous lane*8 bursts). q stored
// pre-scaled by 0.125 (exact in bf16), old [h][n][d] layout. K and V stored
// in fragment order (1KB lane-burst tiles); V carries the in-tile kv perm
// p(t)=(t&15)*4+(t>>4) matching the permuted P tile. Block x==24 (y==0)
// performs the stats reduction over 2080 pair-partials.
__global__ __launch_bounds__(256) void qkv_gemm(
    const unsigned short* __restrict__ x, const unsigned short* __restrict__ w,
    const float* __restrict__ b,
    unsigned short* __restrict__ q, unsigned short* __restrict__ k,
    unsigned short* __restrict__ vt,
    const double* __restrict__ partials, float* __restrict__ neg_inv_std) {
    __shared__ unsigned short stage[64][72];   // 9216 B; padded rows (16B-aligned)
    __shared__ double rs[256], rs2[256];
    int lane = threadIdx.x & 63, wave = threadIdx.x >> 6;
    int l16 = lane & 15, quad = lane >> 4;

    if (blockIdx.x == 24) {                // stats block (y==0 only)
        if (blockIdx.y != 0) return;
        int tid = threadIdx.x;
        double s = 0.0, s2 = 0.0;
        for (int i = tid; i < 2080; i += 256) {
            s += partials[2 * i];
            s2 += partials[2 * i + 1];
        }
        rs[tid] = s; rs2[tid] = s2;
        __syncthreads();
        for (int off = 128; off > 0; off >>= 1) {
            if (tid < off) { rs[tid] += rs[tid + off]; rs2[tid] += rs2[tid + off]; }
            __syncthreads();
        }
        if (tid == 0) {
            double n = 16777216.0;
            double mean = rs[0] / n;
            double var = (rs2[0] - n * mean * mean) / (n - 1.0);  // ddof=1
            *neg_inv_std = (float)(-1.0 / sqrt(var));
        }
        return;
    }

    int m0 = blockIdx.y * 64 + wave * 16;
    int n0 = blockIdx.x * 64;

    const unsigned short* abase = x + (size_t)(blockIdx.y * 4 + wave) * 8192 + lane * 8;
    f32x4 acc[4];
#pragma unroll
    for (int nb = 0; nb < 4; nb++) acc[nb] = (f32x4){0.f, 0.f, 0.f, 0.f};

    for (int k0 = 0; k0 < 512; k0 += 32) {
        bf16x8 af = *(const bf16x8*)(abase + (k0 >> 5) * 512);
#pragma unroll
        for (int nb = 0; nb < 4; nb++) {
            bf16x8 bf = *(const bf16x8*)(w + (size_t)((n0 >> 4) + nb) * 8192
                                           + (k0 >> 5) * 512 + lane * 8);
            acc[nb] = MFMA16(af, bf, acc[nb]);
        }
    }
    if (blockIdx.x < 8) {                  // Q blocks: direct store, old layout
#pragma unroll
        for (int nb = 0; nb < 4; nb++) {
            int j = n0 + nb * 16 + l16;
            float bj = b[j];
            int h = j >> 6, d = j & 63;
#pragma unroll
            for (int r = 0; r < 4; r++) {
                int n = m0 + quad * 4 + r;
                q[((size_t)h * 4096 + n) * 64 + d] = f2b((acc[nb][r] + bj) * 0.125f);
            }
        }
    } else if (blockIdx.x < 16) {          // K block: one head, fragment layout
        int h = blockIdx.x - 8;
        // stage[n_local][d]
#pragma unroll
        for (int nb = 0; nb < 4; nb++) {
            int d = nb * 16 + l16;
            float bj = b[512 + h * 64 + d];
#pragma unroll
            for (int r = 0; r < 4; r++)
                stage[wave * 16 + quad * 4 + r][d] = f2b(acc[nb][r] + bj);
        }
        __syncthreads();
        // 4096 elems = 512 runs of 8; 2 passes x 256 threads
        unsigned short* kb = k + ((size_t)h << 18) + (size_t)blockIdx.y * 4096;
#pragma unroll
        for (int p = 0; p < 2; p++) {
            int rid = p * 256 + threadIdx.x;      // 0..511
            int t = rid >> 7;                     // tile (16 rows)
            int rem = rid & 127;
            int half = rem >> 6, qd = (rem >> 4) & 3, l = rem & 15;
            const unsigned short* src = &stage[t * 16 + l][half * 32 + qd * 8];
            unsigned short* dst = kb + t * 1024 + half * 512 + qd * 128 + l * 8;
            *(uint4*)dst = *(const uint4*)src;
        }
    } else {                               // V block: one head, transpose + fragment layout
        int h = blockIdx.x - 16;
#pragma unroll
        for (int nb = 0; nb < 4; nb++) {
            int d = nb * 16 + l16;
            float bj = b[1024 + h * 64 + d];
            // permuted local token index: p(wave*16+quad*4+r) = quad*16+r*4+wave
#pragma unroll
            for (int r = 0; r < 4; r++)
                stage[d][quad * 16 + r * 4 + wave] = f2b(acc[nb][r] + bj);
        }
        __syncthreads();
        int t = threadIdx.x;
        int d = t >> 2;                    // 0..63
        int nq = (t & 3) * 16;             // 0,16,32,48 (stored-kv within 64-blk)
        unsigned short* dst = vt + ((size_t)h << 18) + (size_t)blockIdx.y * 4096
                            + (d >> 4) * 1024 + ((nq >> 5) & 1) * 512
                            + ((nq >> 3) & 3) * 128 + (d & 15) * 8;
        const unsigned short* src = &stage[d][nq];
        *(uint4*)dst = *(const uint4*)src;         // runs e=0..7 (quad g)
        *(uint4*)(dst + 128) = *(const uint4*)(src + 8);  // quad g+1
    }
}

// ---------------------------------------------------------------- flash attention
// Block = 512 thr = 8 waves = (2 q-groups x 4 kv-quarters), 1 head x 32
// q-rows. Grid 1024. XCD swizzle: xcd=b&7, j=b>>3; h=(xcd&3)*2+(j&1);
// qs=(xcd>>2)*64+(j>>1). Bias single-buffered with in-step prefetch (R29).
// V fragments hoisted above exp/pack; s_setprio around MFMA clusters. No
// max-subtraction; P permuted b64. Epilogue writes att in FRAGMENT order.
__device__ __forceinline__ void attn_step(
    const unsigned short* __restrict__ kptr, const unsigned short* __restrict__ vtp,
    short* __restrict__ pb, int h, int kv0, int lane, int l16, int quad,
    bf16x8 qf0, bf16x8 qf1, float4 (&dv)[4], const float* __restrict__ drow,
    int kv_next, float nis, f32x4 (&o)[4], float (&lam)[4]) {
    size_t tbase = ((size_t)h << 18) + ((size_t)kv0 << 6) + lane * 8;
    const unsigned short* kb = kptr + tbase;
    const unsigned short* vb = vtp + tbase;
    f32x4 s[4];
    __builtin_amdgcn_s_setprio(1);
#pragma unroll
    for (int cb = 0; cb < 4; cb++) {
        bf16x8 kf0 = *(const bf16x8*)(kb + cb * 1024);
        bf16x8 kf1 = *(const bf16x8*)(kb + cb * 1024 + 512);
        f32x4 z = (f32x4){0.f, 0.f, 0.f, 0.f};
        z = MFMA16(qf0, kf0, z);
        z = MFMA16(qf1, kf1, z);
        s[cb] = z;
    }
    __builtin_amdgcn_s_setprio(0);
    // hoisted V fragment loads: latency hides under bias+exp+pack below
    bf16x8 vf[8];
#pragma unroll
    for (int db = 0; db < 4; db++) {
        vf[2 * db]     = *(const bf16x8*)(vb + db * 1024);
        vf[2 * db + 1] = *(const bf16x8*)(vb + db * 1024 + 512);
    }
    // bias (q pre-scaled; permuted dist: .x->cb0 .y->cb1 .z->cb2 .w->cb3)
#pragma unroll
    for (int r = 0; r < 4; r++) {
        s[0][r] = fmaf(dv[r].x, nis, s[0][r]);
        s[1][r] = fmaf(dv[r].y, nis, s[1][r]);
        s[2][r] = fmaf(dv[r].z, nis, s[2][r]);
        s[3][r] = fmaf(dv[r].w, nis, s[3][r]);
    }
    // prefetch next step's bias into the same buffer (use after next QK)
#pragma unroll
    for (int r = 0; r < 4; r++)
        dv[r] = *(const float4*)(drow + (size_t)r * 4096 + kv_next);
    // exp (no max-sub), per-lane partial sums, pack P permuted: pos l16*4+cb
#pragma unroll
    for (int r = 0; r < 4; r++) {
        float p0 = __expf(s[0][r]);
        float p1 = __expf(s[1][r]);
        float p2 = __expf(s[2][r]);
        float p3 = __expf(s[3][r]);
        lam[r] += (p0 + p1) + (p2 + p3);
        unsigned int w0 = (unsigned int)f2b(p0) | ((unsigned int)f2b(p1) << 16);
        unsigned int w1 = (unsigned int)f2b(p2) | ((unsigned int)f2b(p3) << 16);
        uint2 pk; pk.x = w0; pk.y = w1;
        *(uint2*)(pb + (quad * 4 + r) * 72 + l16 * 4) = pk;
    }
    bf16x8 pf0 = *(const bf16x8*)(pb + l16 * 72 + quad * 8);
    bf16x8 pf1 = *(const bf16x8*)(pb + l16 * 72 + 32 + quad * 8);
    __builtin_amdgcn_s_setprio(1);
#pragma unroll
    for (int db = 0; db < 4; db++) {
        o[db] = MFMA16(pf0, vf[2 * db], o[db]);
        o[db] = MFMA16(pf1, vf[2 * db + 1], o[db]);
    }
    __builtin_amdgcn_s_setprio(0);
}

__global__ __launch_bounds__(512, 4) void attn_kernel(
    const unsigned short* __restrict__ q, const unsigned short* __restrict__ k,
    const unsigned short* __restrict__ vt, const float* __restrict__ dist,
    const float* __restrict__ nis_p, unsigned short* __restrict__ att) {
    __shared__ __align__(16) char smem[18432];   // 8x pbuf (16x72 u16) | obuf+lbuf
    int tid = threadIdx.x;
    int lane = tid & 63, wave = tid >> 6;        // wave 0..7
    int l16 = lane & 15, quad = lane >> 4;
    int b = blockIdx.x;
    int xcd = b & 7, j = b >> 3;                 // j 0..127
    int h  = (xcd & 3) * 2 + (j & 1);            // head for whole block
    int qs = (xcd >> 2) * 64 + (j >> 1);         // 32-row q-group, 0..127
    int qgl = wave & 1;                          // local q-group (16 rows)
    int qt = wave >> 1;                          // kv quarter
    int q0 = qs * 32 + qgl * 16;
    int kvbase = qt * 1024;
    float nis = *nis_p;

    short* pb = (short*)smem + wave * 1152;      // 16 x 72

    const unsigned short* qbase = q + ((size_t)h * 4096 + q0 + l16) * 64 + quad * 8;
    bf16x8 qf0 = *(const bf16x8*)(qbase);
    bf16x8 qf1 = *(const bf16x8*)(qbase + 32);

    f32x4 o[4];
    float lam[4];
#pragma unroll
    for (int r = 0; r < 4; r++) {
        lam[r] = 0.f;
        o[0][r] = 0.f; o[1][r] = 0.f; o[2][r] = 0.f; o[3][r] = 0.f;
    }

    const float* drow = dist + (size_t)(q0 + quad * 4) * 4096 + l16 * 4;
    float4 dv[4];
#pragma unroll
    for (int r = 0; r < 4; r++)
        dv[r] = *(const float4*)(drow + (size_t)r * 4096 + kvbase);

    for (int it = 0; it < 16; ++it) {
        int kv0 = kvbase + it * 64;
        int kvn = (it == 15) ? kvbase : kv0 + 64;
        attn_step(k, vt, pb, h, kv0, lane, l16, quad, qf0, qf1, dv, drow, kvn,
                  nis, o, lam);
    }

    // deferred row-sum reduction (16-lane groups share a row)
#pragma unroll
    for (int r = 0; r < 4; r++)
#pragma unroll
        for (int off = 1; off < 16; off <<= 1)
            lam[r] += __shfl_xor(lam[r], off, 64);

    // -------- block-level merge across 4 kv-quarters: plain sums
    __syncthreads();                        // all waves done with pbuf
    float* obuf = (float*)smem;             // [2 qgl][16 row][64 d] = 8 KiB
    float* lbuf = (float*)(smem + 8192);    // [4 quarter][32 row]
    if (l16 == 0)                           // disjoint per quarter: no race
#pragma unroll
        for (int r = 0; r < 4; r++)
            lbuf[qt * 32 + qgl * 16 + quad * 4 + r] = lam[r];
    if (qt == 0) {
#pragma unroll
        for (int db = 0; db < 4; db++)
#pragma unroll
            for (int r = 0; r < 4; r++)
                obuf[(qgl * 16 + quad * 4 + r) * 64 + db * 16 + l16] = o[db][r];
    }
    __syncthreads();
    if (qt == 1) {
#pragma unroll
        for (int db = 0; db < 4; db++)
#pragma unroll
            for (int r = 0; r < 4; r++)
                obuf[(qgl * 16 + quad * 4 + r) * 64 + db * 16 + l16] += o[db][r];
    }
    __syncthreads();
    if (qt == 2) {
#pragma unroll
        for (int db = 0; db < 4; db++)
#pragma unroll
            for (int r = 0; r < 4; r++)
                obuf[(qgl * 16 + quad * 4 + r) * 64 + db * 16 + l16] += o[db][r];
    }
    __syncthreads();
    if (qt == 3) {
#pragma unroll
        for (int db = 0; db < 4; db++)
#pragma unroll
            for (int r = 0; r < 4; r++)
                obuf[(qgl * 16 + quad * 4 + r) * 64 + db * 16 + l16] += o[db][r];
    }
    __syncthreads();

    // 512 threads write 32 rows x 64 cols (one head): 4 cols/thread,
    // att in FRAGMENT order: off = g*8192 + c*512 + qd*128 + l*8 + e
    int rl = tid >> 4;                  // 0..31 local row
    int d4 = (tid & 15) * 4;            // 0..60
    float L = lbuf[rl] + lbuf[32 + rl] + lbuf[64 + rl] + lbuf[96 + rl];
    float rinv = 1.0f / L;
    const float* ob = obuf + rl * 64 + d4;
    ushort4 ua;
    ua.x = f2b(ob[0] * rinv); ua.y = f2b(ob[1] * rinv);
    ua.z = f2b(ob[2] * rinv); ua.w = f2b(ob[3] * rinv);
    int row = qs * 32 + rl;
    int col = h * 64 + d4;
    size_t dst = (size_t)(row >> 4) * 8192 + (col >> 5) * 512
               + ((col >> 3) & 3) * 128 + (row & 15) * 8 + (col & 7);
    *(ushort4*)(att + dst) = ua;
}

// ---------------------------------------------------------------- output GEMM (fp32 store)
// att and w read in fragment order (contiguous lane*8 bursts).
__global__ __launch_bounds__(256) void out_gemm(
    const unsigned short* __restrict__ att, const unsigned short* __restrict__ w,
    const float* __restrict__ b, float* __restrict__ out) {
    int lane = threadIdx.x & 63, wave = threadIdx.x >> 6;
    int l16 = lane & 15, quad = lane >> 4;
    int m0 = blockIdx.y * 64 + wave * 16;
    int n0 = blockIdx.x * 64;

    const unsigned short* abase = att + (size_t)(blockIdx.y * 4 + wave) * 8192 + lane * 8;
    f32x4 acc[4];
#pragma unroll
    for (int nb = 0; nb < 4; nb++) acc[nb] = (f32x4){0.f, 0.f, 0.f, 0.f};

    for (int k0 = 0; k0 < 512; k0 += 32) {
        bf16x8 af = *(const bf16x8*)(abase + (k0 >> 5) * 512);
#pragma unroll
        for (int nb = 0; nb < 4; nb++) {
            bf16x8 bf = *(const bf16x8*)(w + (size_t)((n0 >> 4) + nb) * 8192
                                           + (k0 >> 5) * 512 + lane * 8);
            acc[nb] = MFMA16(af, bf, acc[nb]);
        }
    }
#pragma unroll
    for (int nb = 0; nb < 4; nb++) {
        float bj = b[n0 + nb * 16 + l16];
#pragma unroll
        for (int r = 0; r < 4; r++)
            out[(size_t)(m0 + quad * 4 + r) * 512 + n0 + nb * 16 + l16] =
                acc[nb][r] + bj;
    }
}

extern "C" void kernel_launch(void* const* d_in, const int* in_sizes, int n_in,
                              void* d_out, int out_size, void* d_ws, size_t ws_size,
                              hipStream_t stream) {
    const float* x    = (const float*)d_in[0];
    const float* lat  = (const float*)d_in[1];
    const float* lon  = (const float*)d_in[2];
    const float* wqkv = (const float*)d_in[3];
    const float* bqkv = (const float*)d_in[4];
    const float* wout = (const float*)d_in[5];
    const float* bout = (const float*)d_in[6];
    float* out = (float*)d_out;

    char* ws = (char*)d_ws;
    float* dist        = (float*)ws;                                  // 64 MiB
    double* partials   = (double*)(ws + 67108864);                    // 64 KiB
    float* nis         = (float*)(ws + 67108864 + 65536);             // 64 B
    unsigned short* q  = (unsigned short*)(ws + 67108864 + 65600);
    unsigned short* k  = q  + (size_t)8 * 4096 * 64;   // 4 MiB each
    unsigned short* vt = k  + (size_t)8 * 4096 * 64;
    unsigned short* att = vt + (size_t)8 * 4096 * 64;
    unsigned short* xb  = att + (size_t)4096 * 512;
    unsigned short* wqb = xb  + (size_t)4096 * 512;
    unsigned short* wob = wqb + (size_t)1536 * 512;

    prep_kernel<<<3616, 256, 0, stream>>>(lat, lon, dist, partials,
                                          x, xb, wqkv, wqb, wout, wob);
    qkv_gemm<<<dim3(25, 64), 256, 0, stream>>>(xb, wqb, bqkv, q, k, vt,
                                               partials, nis);
    attn_kernel<<<1024, 512, 0, stream>>>(q, k, vt, dist, nis, att);
    out_gemm<<<dim3(8, 64), 256, 0, stream>>>(att, wob, bout, out);
}